// Round 10
// baseline (346.034 us; speedup 1.0000x reference)
//
#include <hip/hip_runtime.h>
#include <hip/hip_bf16.h>

#define BB 32
#define TT 256
#define MM 16
#define DD 128
#define HH 128

typedef unsigned int uint;
typedef unsigned short ushort;
typedef short s16x8 __attribute__((ext_vector_type(8)));
typedef float f32x4 __attribute__((ext_vector_type(4)));

__device__ __forceinline__ float bl16(uint u){ return __uint_as_float(u << 16); }
__device__ __forceinline__ float bh16(uint u){ return __uint_as_float(u & 0xffff0000u); }

__device__ __forceinline__ ushort f2bu(float f){
  __hip_bfloat16 h = __float2bfloat16(f);
  return *(ushort*)&h;
}

__device__ __forceinline__ float hsig(float x){
  return fminf(fmaxf(fmaf(x, 0.2f, 0.5f), 0.0f), 1.0f);
}
__device__ __forceinline__ float tanh_f(float x){
  return 1.0f - 2.0f / (__expf(2.0f * x) + 1.0f);   // saturates correctly
}

// ---------------- K_init: dtype probe (flag=1 bf16, 0 fp32) + v_x[d] = sum_h W_a[d,h]
__global__ __launch_bounds__(128) void k_init(const void* __restrict__ xraw,
                                              const void* __restrict__ Wa,
                                              int* __restrict__ flag,
                                              float* __restrict__ vx){
  __shared__ int cnt[128];
  __shared__ int smode;
  int tid = threadIdx.x;
  const ushort* u = (const ushort*)xraw;
  int c = 0;
  for (int j = 0; j < 16; ++j){
    ushort v = u[2 * (tid * 16 + j)];
    float f = __uint_as_float(((uint)v) << 16);
    if (f == f && fabsf(f) < 64.f && fabsf(f) > 1e-12f) ++c;
  }
  cnt[tid] = c;
  __syncthreads();
  if (tid == 0){
    int s = 0;
    for (int j = 0; j < 128; ++j) s += cnt[j];
    int m = (s > 1024) ? 1 : 0;
    smode = m; *flag = m;
  }
  __syncthreads();
  int mode = smode;

  int d = tid;
  float s = 0.f;
  if (mode){
    const uint4* row = (const uint4*)((const ushort*)Wa + d * HH);
    #pragma unroll
    for (int q = 0; q < 16; ++q){
      uint4 v = row[q];
      s += bl16(v.x) + bh16(v.x) + bl16(v.y) + bh16(v.y)
         + bl16(v.z) + bh16(v.z) + bl16(v.w) + bh16(v.w);
    }
  } else {
    const float4* row = (const float4*)((const float*)Wa + d * HH);
    #pragma unroll
    for (int q = 0; q < 32; ++q){
      float4 v = row[q];
      s += v.x + v.y + v.z + v.w;
    }
  }
  vx[d] = s;
}

// ---------------- K_uprep: pack U as MFMA B-operand fragments (bf16) ----------------
// B-frag layout for mfma_f32_16x16x32_bf16: lane holds B[k=quad*8+jj][n=lane&15],
// jj=0..7 (8 bf16 = 4 dwords). Uw flat dword idx = (((w*4+ct)*4+ks)*64 + lane)*4 + d:
// n = w*64 + ct*16 + (lane&15), k = ks*32 + (lane>>4)*8 + 2d (+1 for high half).
// Same fragments serve every block (all blocks use the same U).
__global__ __launch_bounds__(256) void k_uprep(
  const void* __restrict__ Ui, const void* __restrict__ Uf,
  const void* __restrict__ Uc, const void* __restrict__ Uo,
  const int* __restrict__ flag, uint* __restrict__ Uw)
{
  int mode = *flag;
  int idx = blockIdx.x * 256 + threadIdx.x;   // 0..32767
  int d    = idx & 3;
  int lane = (idx >> 2) & 63;
  int ks   = (idx >> 8) & 3;
  int ct   = (idx >> 10) & 3;
  int w    = (idx >> 12) & 7;
  int n = w * 64 + ct * 16 + (lane & 15);
  int g = n >> 7, j = n & 127;
  int k = ks * 32 + (lane >> 4) * 8 + 2 * d;
  const void* Ugs[4] = {Ui, Uf, Uc, Uo};
  float ux, uy;
  if (mode){
    const ushort* U16 = (const ushort*)Ugs[g];
    ux = __uint_as_float(((uint)U16[(size_t)k * HH + j]) << 16);
    uy = __uint_as_float(((uint)U16[(size_t)(k + 1) * HH + j]) << 16);
  } else {
    const float* U32 = (const float*)Ugs[g];
    ux = U32[(size_t)k * HH + j];
    uy = U32[(size_t)(k + 1) * HH + j];
  }
  Uw[idx] = (uint)f2bu(ux) | ((uint)f2bu(uy) << 16);
}

// ---------------- K1: softmax-pool, 2 (b,t)-tiles per block -------------------------
__global__ __launch_bounds__(256) void k_pool(const void* __restrict__ xraw,
                                              const int* __restrict__ flag,
                                              const float* __restrict__ vx,
                                              __hip_bfloat16* __restrict__ newx){
  __shared__ float xs[2][MM][DD];   // 16 KB
  __shared__ float vxs[DD];
  __shared__ float part[2][128];
  __shared__ float sc[2][MM];
  int mode = *flag;
  int tid = threadIdx.x;
  int half = tid >> 7, t2 = tid & 127;
  int bt = blockIdx.x * 2 + half;       // tile 0..8191
  int b = bt >> 8, t = bt & 255;

  float* xdst = &xs[half][0][0];        // 2048 floats per tile
  if (mode){
    const uint4* s = (const uint4*)((const ushort*)xraw + (size_t)bt * 2048);
    #pragma unroll
    for (int q = 0; q < 2; ++q){
      int ch = t2 + 128 * q;
      uint4 v = s[ch];
      float* d = &xdst[ch * 8];
      d[0] = bl16(v.x); d[1] = bh16(v.x);
      d[2] = bl16(v.y); d[3] = bh16(v.y);
      d[4] = bl16(v.z); d[5] = bh16(v.z);
      d[6] = bl16(v.w); d[7] = bh16(v.w);
    }
  } else {
    const float4* s = (const float4*)((const float*)xraw + (size_t)bt * 2048);
    #pragma unroll
    for (int q = 0; q < 4; ++q){
      int ch = t2 + 128 * q;
      *(float4*)&xdst[ch * 4] = s[ch];
    }
  }
  if (tid < DD) vxs[tid] = vx[tid];
  __syncthreads();

  int m = t2 >> 3, cc = t2 & 7;
  float p = 0.f;
  #pragma unroll
  for (int j = 0; j < 16; ++j)
    p = fmaf(xs[half][m][cc * 16 + j], vxs[cc * 16 + j], p);
  part[half][t2] = p;
  __syncthreads();
  if (t2 < MM){
    float s = 0.f;
    #pragma unroll
    for (int q = 0; q < 8; ++q) s += part[half][t2 * 8 + q];
    sc[half][t2] = s;
  }
  __syncthreads();

  float mx = sc[half][0];
  #pragma unroll
  for (int m2 = 1; m2 < MM; ++m2) mx = fmaxf(mx, sc[half][m2]);
  float wgt[MM]; float den = 0.f;
  #pragma unroll
  for (int m2 = 0; m2 < MM; ++m2){ wgt[m2] = __expf(sc[half][m2] - mx); den += wgt[m2]; }
  float inv = 1.0f / den;

  float acc = 0.f;
  #pragma unroll
  for (int m2 = 0; m2 < MM; ++m2)
    acc = fmaf(wgt[m2], xs[half][m2][t2], acc);
  newx[((size_t)t * BB + b) * DD + t2] = __float2bfloat16(acc * inv);
}

// ---------------- K2: Xp[r, g*128+j] = b_g[j] + sum_d new_x[r,d] * W_g[d,j] ---------
__global__ __launch_bounds__(256) void k_xproj(const __hip_bfloat16* __restrict__ nx,
  const void* __restrict__ W0, const void* __restrict__ W1,
  const void* __restrict__ W2, const void* __restrict__ W3,
  const void* __restrict__ b0_, const void* __restrict__ b1_,
  const void* __restrict__ b2_, const void* __restrict__ b3_,
  const int* __restrict__ flag, float* __restrict__ Xp)
{
  __shared__ __hip_bfloat16 As[128][DD];  // 32 KB
  __shared__ __hip_bfloat16 Ws[DD][HH];   // 32 KB
  int mode = *flag;
  int tid = threadIdx.x;
  int r0 = blockIdx.x * 128;
  int g  = blockIdx.y;
  const void* W  = (g == 0) ? W0  : (g == 1) ? W1  : (g == 2) ? W2  : W3;
  const void* bb = (g == 0) ? b0_ : (g == 1) ? b1_ : (g == 2) ? b2_ : b3_;

  const uint4* asrc = (const uint4*)(nx + (size_t)r0 * DD);
  uint4* adst = (uint4*)&As[0][0];
  uint4* wdst = (uint4*)&Ws[0][0];
  #pragma unroll
  for (int q = 0; q < 8; ++q) adst[q * 256 + tid] = asrc[q * 256 + tid];

  if (mode){
    const uint4* wsrc = (const uint4*)W;
    #pragma unroll
    for (int q = 0; q < 8; ++q) wdst[q * 256 + tid] = wsrc[q * 256 + tid];
  } else {
    const float4* wsrc = (const float4*)W;
    #pragma unroll
    for (int q = 0; q < 8; ++q){
      int ch = q * 256 + tid;
      float4 a = wsrc[2 * ch], b = wsrc[2 * ch + 1];
      uint4 o;
      o.x = (uint)f2bu(a.x) | ((uint)f2bu(a.y) << 16);
      o.y = (uint)f2bu(a.z) | ((uint)f2bu(a.w) << 16);
      o.z = (uint)f2bu(b.x) | ((uint)f2bu(b.y) << 16);
      o.w = (uint)f2bu(b.z) | ((uint)f2bu(b.w) << 16);
      wdst[ch] = o;
    }
  }
  __syncthreads();

  int ti = tid >> 4, tj = tid & 15;
  int i0 = ti * 8, j0 = tj * 8;
  float acc[8][8] = {};

  for (int k = 0; k < DD; k += 8){
    float a[8][8];
    #pragma unroll
    for (int ii = 0; ii < 8; ++ii){
      uint4 v = *(const uint4*)&As[i0 + ii][k];
      a[ii][0] = bl16(v.x); a[ii][1] = bh16(v.x);
      a[ii][2] = bl16(v.y); a[ii][3] = bh16(v.y);
      a[ii][4] = bl16(v.z); a[ii][5] = bh16(v.z);
      a[ii][6] = bl16(v.w); a[ii][7] = bh16(v.w);
    }
    #pragma unroll
    for (int kk = 0; kk < 8; ++kk){
      uint4 v = *(const uint4*)&Ws[k + kk][j0];
      float w[8];
      w[0] = bl16(v.x); w[1] = bh16(v.x);
      w[2] = bl16(v.y); w[3] = bh16(v.y);
      w[4] = bl16(v.z); w[5] = bh16(v.z);
      w[6] = bl16(v.w); w[7] = bh16(v.w);
      #pragma unroll
      for (int ii = 0; ii < 8; ++ii)
        #pragma unroll
        for (int jj = 0; jj < 8; ++jj)
          acc[ii][jj] = fmaf(a[ii][kk], w[jj], acc[ii][jj]);
    }
  }

  float bias[8];
  if (mode){
    #pragma unroll
    for (int jj = 0; jj < 8; ++jj)
      bias[jj] = __uint_as_float(((uint)((const ushort*)bb)[j0 + jj]) << 16);
  } else {
    #pragma unroll
    for (int jj = 0; jj < 8; ++jj) bias[jj] = ((const float*)bb)[j0 + jj];
  }
  #pragma unroll
  for (int ii = 0; ii < 8; ++ii){
    size_t r = (size_t)(r0 + i0 + ii);
    float* orow = &Xp[r * 512 + g * HH + j0];
    float4 o1 = make_float4(acc[ii][0] + bias[0], acc[ii][1] + bias[1],
                            acc[ii][2] + bias[2], acc[ii][3] + bias[3]);
    float4 o2 = make_float4(acc[ii][4] + bias[4], acc[ii][5] + bias[5],
                            acc[ii][6] + bias[6], acc[ii][7] + bias[7]);
    *(float4*)orow       = o1;
    *(float4*)(orow + 4) = o2;
  }
}

// ---------------- K3: recurrence via MFMA. 8 blocks x 4 batches ---------------------
// Per step: P(4x512) = H(4x128) @ U(128x512) with mfma_f32_16x16x32_bf16 (M=4 of 16
// rows used). Wave w owns 64 cols (4 C-tiles x 4 K-steps = 16 MFMAs). H lives in LDS
// in A-layout (row-padded 136 ushorts -> 2-way-free banks); U B-frags preloaded into
// regs/AGPRs (MFMA reads AGPRs natively on gfx950 -> allocator-proof, unlike R7-R9).
// C-layout (M=4) = quad-0 lanes regs 0-3 -> b128 store to plds[g][j][m]; gate thread
// (m=tid&3, j=tid>>2) reads at dword g*512+tid (conflict-free). One state per thread,
// c in registers, 2 barriers/step.
__global__ __launch_bounds__(512) void k_rec(const float* __restrict__ Xp,
  const uint* __restrict__ Uw, float* __restrict__ out)
{
  __shared__ ushort hlds[2][16][136];   // 8704 B, rows 4..15 stay zero
  __shared__ float  plds[4][128][4];    // 8192 B  [g][j][m]
  int tid  = threadIdx.x;
  int lane = tid & 63;
  int w    = tid >> 6;                  // wave 0..7
  int b0   = blockIdx.x * 4;            // first batch of this block
  int gm   = tid & 3;                   // gate-thread: batch row m
  int gj   = tid >> 2;                  // gate-thread: column j (0..127)

  // B fragments: 16 per thread (ct,ks), 4 dwords each
  union { uint4 u; s16x8 s; } Bf[16];
  {
    const uint4* Ub = (const uint4*)Uw;
    #pragma unroll
    for (int ct = 0; ct < 4; ++ct)
      #pragma unroll
      for (int ks = 0; ks < 4; ++ks)
        Bf[ct * 4 + ks].u = Ub[((w * 4 + ct) * 4 + ks) * 64 + lane];
  }

  // zero both h buffers (4352 ushorts = 2176 uints)
  for (int i = tid; i < 2176; i += 512) ((uint*)hlds)[i] = 0;
  float cst = 0.f, vh = 0.f;
  const float* xrow = Xp + (size_t)(b0 + gm) * 512 + gj;  // + t*16384 + g*128
  __syncthreads();

  int m = lane & 15, quad = lane >> 4;
  for (int t = 0; t < TT; ++t){
    // this step's x-presums (used after the barrier; latency hidden by MFMA phase)
    size_t xo = (size_t)t * (BB * 512);
    float x0 = xrow[xo];
    float x1 = xrow[xo + 128];
    float x2 = xrow[xo + 256];
    float x3 = xrow[xo + 384];

    int p = t & 1;
    // A fragments: A[m][k=ks*32+quad*8+jj] from hlds[p]
    const ushort* hr = &hlds[p][m][quad * 8];
    union { uint4 u; s16x8 s; } Af[4];
    #pragma unroll
    for (int ks = 0; ks < 4; ++ks)
      Af[ks].u = *(const uint4*)(hr + ks * 32);

    f32x4 acc[4] = {{0,0,0,0},{0,0,0,0},{0,0,0,0},{0,0,0,0}};
    #pragma unroll
    for (int ks = 0; ks < 4; ++ks)
      #pragma unroll
      for (int ct = 0; ct < 4; ++ct)
        acc[ct] = __builtin_amdgcn_mfma_f32_16x16x32_bf16(Af[ks].s, Bf[ct * 4 + ks].s, acc[ct], 0, 0, 0);

    // C rows 0..3 live in quad 0, regs 0..3 -> b128 per (ct)
    if (lane < 16){
      int g = w >> 1;
      #pragma unroll
      for (int ct = 0; ct < 4; ++ct){
        int j = (w & 1) * 64 + ct * 16 + lane;
        *(f32x4*)&plds[g][j][0] = acc[ct];
      }
    }
    __syncthreads();

    // gate phase: one (m,j) state per thread; plds read = dword g*512+tid
    float pi = plds[0][gj][gm] + x0;
    float pf = plds[1][gj][gm] + x1;
    float pc = plds[2][gj][gm] + x2;
    float po = plds[3][gj][gm] + x3;
    float ig = hsig(pi), fg = hsig(pf), og = hsig(po);
    float gg = tanh_f(pc);
    cst = fmaf(fg, cst, ig * gg);
    vh  = og * tanh_f(cst);
    hlds[1 - p][gm][gj] = f2bu(vh);
    __syncthreads();
  }

  out[(b0 + gm) * HH + gj] = vh;
}

extern "C" void kernel_launch(void* const* d_in, const int* in_sizes, int n_in,
                              void* d_out, int out_size, void* d_ws, size_t ws_size,
                              hipStream_t stream) {
  (void)in_sizes; (void)n_in; (void)out_size; (void)ws_size;

  // ---- workspace layout (~18.2 MB) ----
  // [0,16)            flag
  // [16,528)          vx fp32[128]
  // [1024, +128KB)    Uw uint[32768]  (MFMA B-fragments, bf16 pairs)
  // [+, +2MB)         newx bf16[8192*128]
  // [+, +16MB)        Xp fp32[8192*512]
  char* ws = (char*)d_ws;
  int* flag = (int*)ws;
  float* vx = (float*)(ws + 16);
  uint* Uw = (uint*)(ws + 1024);
  __hip_bfloat16* newx = (__hip_bfloat16*)(ws + 1024 + 131072);
  float* Xp = (float*)(ws + 1024 + 131072 + (size_t)2 * 1024 * 1024);

  k_init<<<1, 128, 0, stream>>>(d_in[0], d_in[1], flag, vx);
  k_uprep<<<128, 256, 0, stream>>>(d_in[4], d_in[7], d_in[10], d_in[13], flag, Uw);
  k_pool<<<BB * TT / 2, 256, 0, stream>>>(d_in[0], flag, vx, newx);
  dim3 g2(64, 4);
  k_xproj<<<g2, 256, 0, stream>>>(newx,
      d_in[3], d_in[6], d_in[9], d_in[12],     // W_i, W_f, W_c, W_o
      d_in[5], d_in[8], d_in[11], d_in[14],    // b_i, b_f, b_c, b_o
      flag, Xp);
  k_rec<<<8, 512, 0, stream>>>(Xp, Uw, (float*)d_out);
}

// Round 11
// 303.089 us; speedup vs baseline: 1.1417x; 1.1417x over previous
//
#include <hip/hip_runtime.h>
#include <hip/hip_bf16.h>
#include <hip/hip_fp16.h>

#define BB 32
#define TT 256
#define MM 16
#define DD 128
#define HH 128

typedef unsigned int uint;
typedef unsigned short ushort;

__device__ __forceinline__ float bl16(uint u){ return __uint_as_float(u << 16); }
__device__ __forceinline__ float bh16(uint u){ return __uint_as_float(u & 0xffff0000u); }

__device__ __forceinline__ ushort f2bu(float f){
  __hip_bfloat16 h = __float2bfloat16(f);
  return *(ushort*)&h;
}

__device__ __forceinline__ float hsig(float x){
  return fminf(fmaxf(fmaf(x, 0.2f, 0.5f), 0.0f), 1.0f);
}
__device__ __forceinline__ float tanh_f(float x){
  return 1.0f - 2.0f / (__expf(2.0f * x) + 1.0f);   // saturates correctly
}

__device__ __forceinline__ __half2 u2h2(uint u){
  union{uint x; __half2 h;} c; c.x = u; return c.h;
}
__device__ __forceinline__ uint h22u(__half2 h){
  union{__half2 h; uint x;} c; c.h = h; return c.x;
}
__device__ __forceinline__ float h2sumf(__half2 v){
  return __half2float(__low2half(v)) + __half2float(__high2half(v));
}

// quad_perm butterfly: all 4 quad lanes end with the quad sum
__device__ __forceinline__ float qsum4(float v){
  float t1 = __int_as_float(__builtin_amdgcn_mov_dpp(__float_as_int(v), 0xB1, 0xf, 0xf, true)); // [1,0,3,2]
  v += t1;
  float t2 = __int_as_float(__builtin_amdgcn_mov_dpp(__float_as_int(v), 0x4E, 0xf, 0xf, true)); // [2,3,0,1]
  return v + t2;
}

// ---------------- K_init: dtype probe (flag=1 bf16, 0 fp32) + v_x[d] = sum_h W_a[d,h]
__global__ __launch_bounds__(128) void k_init(const void* __restrict__ xraw,
                                              const void* __restrict__ Wa,
                                              int* __restrict__ flag,
                                              float* __restrict__ vx){
  __shared__ int cnt[128];
  __shared__ int smode;
  int tid = threadIdx.x;
  const ushort* u = (const ushort*)xraw;
  int c = 0;
  for (int j = 0; j < 16; ++j){
    ushort v = u[2 * (tid * 16 + j)];
    float f = __uint_as_float(((uint)v) << 16);
    if (f == f && fabsf(f) < 64.f && fabsf(f) > 1e-12f) ++c;
  }
  cnt[tid] = c;
  __syncthreads();
  if (tid == 0){
    int s = 0;
    for (int j = 0; j < 128; ++j) s += cnt[j];
    int m = (s > 1024) ? 1 : 0;
    smode = m; *flag = m;
  }
  __syncthreads();
  int mode = smode;

  int d = tid;
  float s = 0.f;
  if (mode){
    const uint4* row = (const uint4*)((const ushort*)Wa + d * HH);
    #pragma unroll
    for (int q = 0; q < 16; ++q){
      uint4 v = row[q];
      s += bl16(v.x) + bh16(v.x) + bl16(v.y) + bh16(v.y)
         + bl16(v.z) + bh16(v.z) + bl16(v.w) + bh16(v.w);
    }
  } else {
    const float4* row = (const float4*)((const float*)Wa + d * HH);
    #pragma unroll
    for (int q = 0; q < 32; ++q){
      float4 v = row[q];
      s += v.x + v.y + v.z + v.w;
    }
  }
  vx[d] = s;
}

// ---------------- K_uprep: pack U into per-thread-contiguous f16 pairs for k_rec ----
// Uw flat idx = tid*64 + g*16 + ss*4 + m  (tid=(j<<2)|q). Each uint = half2 of
// (U[k][j], U[k+1][j]) with k = 32q + ((ss+q)&3)*8 + 2m  (bank rotation baked in).
__global__ __launch_bounds__(256) void k_uprep(
  const void* __restrict__ Ui, const void* __restrict__ Uf,
  const void* __restrict__ Uc, const void* __restrict__ Uo,
  const int* __restrict__ flag, uint* __restrict__ Uw)
{
  int mode = *flag;
  int idx = blockIdx.x * 256 + threadIdx.x;   // 0..32767
  int tid = idx >> 6;
  int rem = idx & 63;
  int g = rem >> 4, s = rem & 15;
  int ss = s >> 2, m = s & 3;
  int q = tid & 3, j = tid >> 2;
  int kr = (ss + q) & 3;
  int k = 32 * q + kr * 8 + 2 * m;
  const void* Ugs[4] = {Ui, Uf, Uc, Uo};
  float ux, uy;
  if (mode){
    const ushort* U16 = (const ushort*)Ugs[g];
    ux = __uint_as_float(((uint)U16[(size_t)k * HH + j]) << 16);
    uy = __uint_as_float(((uint)U16[(size_t)(k + 1) * HH + j]) << 16);
  } else {
    const float* U32 = (const float*)Ugs[g];
    ux = U32[(size_t)k * HH + j];
    uy = U32[(size_t)(k + 1) * HH + j];
  }
  __half2 hv = __floats2half2_rn(ux, uy);
  Uw[idx] = h22u(hv);
}

// ---------------- K1: softmax-pool, 2 (b,t)-tiles per block -------------------------
__global__ __launch_bounds__(256) void k_pool(const void* __restrict__ xraw,
                                              const int* __restrict__ flag,
                                              const float* __restrict__ vx,
                                              __hip_bfloat16* __restrict__ newx){
  __shared__ float xs[2][MM][DD];   // 16 KB
  __shared__ float vxs[DD];
  __shared__ float part[2][128];
  __shared__ float sc[2][MM];
  int mode = *flag;
  int tid = threadIdx.x;
  int half = tid >> 7, t2 = tid & 127;
  int bt = blockIdx.x * 2 + half;       // tile 0..8191
  int b = bt >> 8, t = bt & 255;

  float* xdst = &xs[half][0][0];        // 2048 floats per tile
  if (mode){
    const uint4* s = (const uint4*)((const ushort*)xraw + (size_t)bt * 2048);
    #pragma unroll
    for (int q = 0; q < 2; ++q){
      int ch = t2 + 128 * q;
      uint4 v = s[ch];
      float* d = &xdst[ch * 8];
      d[0] = bl16(v.x); d[1] = bh16(v.x);
      d[2] = bl16(v.y); d[3] = bh16(v.y);
      d[4] = bl16(v.z); d[5] = bh16(v.z);
      d[6] = bl16(v.w); d[7] = bh16(v.w);
    }
  } else {
    const float4* s = (const float4*)((const float*)xraw + (size_t)bt * 2048);
    #pragma unroll
    for (int q = 0; q < 4; ++q){
      int ch = t2 + 128 * q;
      *(float4*)&xdst[ch * 4] = s[ch];
    }
  }
  if (tid < DD) vxs[tid] = vx[tid];
  __syncthreads();

  int m = t2 >> 3, cc = t2 & 7;
  float p = 0.f;
  #pragma unroll
  for (int j = 0; j < 16; ++j)
    p = fmaf(xs[half][m][cc * 16 + j], vxs[cc * 16 + j], p);
  part[half][t2] = p;
  __syncthreads();
  if (t2 < MM){
    float s = 0.f;
    #pragma unroll
    for (int q = 0; q < 8; ++q) s += part[half][t2 * 8 + q];
    sc[half][t2] = s;
  }
  __syncthreads();

  float mx = sc[half][0];
  #pragma unroll
  for (int m2 = 1; m2 < MM; ++m2) mx = fmaxf(mx, sc[half][m2]);
  float wgt[MM]; float den = 0.f;
  #pragma unroll
  for (int m2 = 0; m2 < MM; ++m2){ wgt[m2] = __expf(sc[half][m2] - mx); den += wgt[m2]; }
  float inv = 1.0f / den;

  float acc = 0.f;
  #pragma unroll
  for (int m2 = 0; m2 < MM; ++m2)
    acc = fmaf(wgt[m2], xs[half][m2][t2], acc);
  newx[((size_t)t * BB + b) * DD + t2] = __float2bfloat16(acc * inv);
}

// ---------------- K2: Xp[r, g*128+j] = b_g[j] + sum_d new_x[r,d] * W_g[d,j] ---------
__global__ __launch_bounds__(256) void k_xproj(const __hip_bfloat16* __restrict__ nx,
  const void* __restrict__ W0, const void* __restrict__ W1,
  const void* __restrict__ W2, const void* __restrict__ W3,
  const void* __restrict__ b0_, const void* __restrict__ b1_,
  const void* __restrict__ b2_, const void* __restrict__ b3_,
  const int* __restrict__ flag, float* __restrict__ Xp)
{
  __shared__ __hip_bfloat16 As[128][DD];  // 32 KB
  __shared__ __hip_bfloat16 Ws[DD][HH];   // 32 KB
  int mode = *flag;
  int tid = threadIdx.x;
  int r0 = blockIdx.x * 128;
  int g  = blockIdx.y;
  const void* W  = (g == 0) ? W0  : (g == 1) ? W1  : (g == 2) ? W2  : W3;
  const void* bb = (g == 0) ? b0_ : (g == 1) ? b1_ : (g == 2) ? b2_ : b3_;

  const uint4* asrc = (const uint4*)(nx + (size_t)r0 * DD);
  uint4* adst = (uint4*)&As[0][0];
  uint4* wdst = (uint4*)&Ws[0][0];
  #pragma unroll
  for (int q = 0; q < 8; ++q) adst[q * 256 + tid] = asrc[q * 256 + tid];

  if (mode){
    const uint4* wsrc = (const uint4*)W;
    #pragma unroll
    for (int q = 0; q < 8; ++q) wdst[q * 256 + tid] = wsrc[q * 256 + tid];
  } else {
    const float4* wsrc = (const float4*)W;
    #pragma unroll
    for (int q = 0; q < 8; ++q){
      int ch = q * 256 + tid;
      float4 a = wsrc[2 * ch], b = wsrc[2 * ch + 1];
      uint4 o;
      o.x = (uint)f2bu(a.x) | ((uint)f2bu(a.y) << 16);
      o.y = (uint)f2bu(a.z) | ((uint)f2bu(a.w) << 16);
      o.z = (uint)f2bu(b.x) | ((uint)f2bu(b.y) << 16);
      o.w = (uint)f2bu(b.z) | ((uint)f2bu(b.w) << 16);
      wdst[ch] = o;
    }
  }
  __syncthreads();

  int ti = tid >> 4, tj = tid & 15;
  int i0 = ti * 8, j0 = tj * 8;
  float acc[8][8] = {};

  for (int k = 0; k < DD; k += 8){
    float a[8][8];
    #pragma unroll
    for (int ii = 0; ii < 8; ++ii){
      uint4 v = *(const uint4*)&As[i0 + ii][k];
      a[ii][0] = bl16(v.x); a[ii][1] = bh16(v.x);
      a[ii][2] = bl16(v.y); a[ii][3] = bh16(v.y);
      a[ii][4] = bl16(v.z); a[ii][5] = bh16(v.z);
      a[ii][6] = bl16(v.w); a[ii][7] = bh16(v.w);
    }
    #pragma unroll
    for (int kk = 0; kk < 8; ++kk){
      uint4 v = *(const uint4*)&Ws[k + kk][j0];
      float w[8];
      w[0] = bl16(v.x); w[1] = bh16(v.x);
      w[2] = bl16(v.y); w[3] = bh16(v.y);
      w[4] = bl16(v.z); w[5] = bh16(v.z);
      w[6] = bl16(v.w); w[7] = bh16(v.w);
      #pragma unroll
      for (int ii = 0; ii < 8; ++ii)
        #pragma unroll
        for (int jj = 0; jj < 8; ++jj)
          acc[ii][jj] = fmaf(a[ii][kk], w[jj], acc[ii][jj]);
    }
  }

  float bias[8];
  if (mode){
    #pragma unroll
    for (int jj = 0; jj < 8; ++jj)
      bias[jj] = __uint_as_float(((uint)((const ushort*)bb)[j0 + jj]) << 16);
  } else {
    #pragma unroll
    for (int jj = 0; jj < 8; ++jj) bias[jj] = ((const float*)bb)[j0 + jj];
  }
  #pragma unroll
  for (int ii = 0; ii < 8; ++ii){
    size_t r = (size_t)(r0 + i0 + ii);
    float* orow = &Xp[r * 512 + g * HH + j0];
    float4 o1 = make_float4(acc[ii][0] + bias[0], acc[ii][1] + bias[1],
                            acc[ii][2] + bias[2], acc[ii][3] + bias[3]);
    float4 o2 = make_float4(acc[ii][4] + bias[4], acc[ii][5] + bias[5],
                            acc[ii][6] + bias[6], acc[ii][7] + bias[7]);
    *(float4*)orow       = o1;
    *(float4*)(orow + 4) = o2;
  }
}

// ---------------- K3: recurrence, f16 matvec. R9 kernel + amdgpu_waves_per_eu(2,2) --
// Grid = 32 blocks x 8 waves on 256 CUs -> exactly 1 block/CU = 2 waves/SIMD; extra
// occupancy is physically impossible, so pin the allocator's target at (2,2) to get
// the ~256-VGPR budget and keep Ur[64] architecturally resident (R7-R10: allocator
// targeted high occupancy, VGPR 48-88, and sank U loads into the loop = 2.2x VALU).
__global__ __attribute__((amdgpu_waves_per_eu(2, 2))) __launch_bounds__(512)
void k_rec(const float* __restrict__ Xp,
  const uint* __restrict__ Uw, float* __restrict__ out)
{
  __shared__ __align__(16) __half hlds[2][HH];   // 512 B
  int tid = threadIdx.x;
  int b   = blockIdx.x;
  int q   = tid & 3;                  // k-quarter; lane q also carries gate q's x
  int j   = tid >> 2;                 // output col 0..127

  float m0 = (q == 0) ? 1.f : 0.f;
  float m1 = (q == 1) ? 1.f : 0.f;
  float m2 = (q == 2) ? 1.f : 0.f;
  float m3 = (q == 3) ? 1.f : 0.f;

  // U regs: flat [g*16 + ss*4 + m], 16 contiguous uint4 loads
  uint Ur[64];
  {
    const uint4* Uwt = (const uint4*)(Uw + (size_t)tid * 64);
    #pragma unroll
    for (int i = 0; i < 16; ++i){
      uint4 v = Uwt[i];
      Ur[4 * i + 0] = v.x; Ur[4 * i + 1] = v.y;
      Ur[4 * i + 2] = v.z; Ur[4 * i + 3] = v.w;
    }
  }

  if (tid < 64) ((uint*)&hlds[0][0])[tid] = 0;   // zero h buffer 0 (128 f16)
  float cst = 0.f, vh = 0.f;
  const float* xb = Xp + (size_t)b * 512 + q * HH + j;   // step stride = 32*512
  float xp = xb[0];
  __syncthreads();

  for (int t = 0; t < TT; ++t){
    // next-step prefetch (t=255 reads the 64KB slack row after Xp; value unused)
    float xpn = xb[(size_t)(t + 1) * (BB * 512)];

    const uint4* hb = (const uint4*)&hlds[t & 1][0];     // 4 uint4 per quarter
    __half2 acc0 = u2h2(0), acc1 = u2h2(0), acc2 = u2h2(0), acc3 = u2h2(0);
    #pragma unroll
    for (int ss = 0; ss < 4; ++ss){
      int kr = (ss + q) & 3;                             // bank-rotated local slot
      uint4 h8 = hb[q * 4 + kr];
      __half2 hp0 = u2h2(h8.x), hp1 = u2h2(h8.y), hp2 = u2h2(h8.z), hp3 = u2h2(h8.w);
      int base = ss * 4;
      acc0 = __hfma2(hp0, u2h2(Ur[ 0 + base]), acc0);
      acc0 = __hfma2(hp1, u2h2(Ur[ 1 + base]), acc0);
      acc0 = __hfma2(hp2, u2h2(Ur[ 2 + base]), acc0);
      acc0 = __hfma2(hp3, u2h2(Ur[ 3 + base]), acc0);
      acc1 = __hfma2(hp0, u2h2(Ur[16 + base]), acc1);
      acc1 = __hfma2(hp1, u2h2(Ur[17 + base]), acc1);
      acc1 = __hfma2(hp2, u2h2(Ur[18 + base]), acc1);
      acc1 = __hfma2(hp3, u2h2(Ur[19 + base]), acc1);
      acc2 = __hfma2(hp0, u2h2(Ur[32 + base]), acc2);
      acc2 = __hfma2(hp1, u2h2(Ur[33 + base]), acc2);
      acc2 = __hfma2(hp2, u2h2(Ur[34 + base]), acc2);
      acc2 = __hfma2(hp3, u2h2(Ur[35 + base]), acc2);
      acc3 = __hfma2(hp0, u2h2(Ur[48 + base]), acc3);
      acc3 = __hfma2(hp1, u2h2(Ur[49 + base]), acc3);
      acc3 = __hfma2(hp2, u2h2(Ur[50 + base]), acc3);
      acc3 = __hfma2(hp3, u2h2(Ur[51 + base]), acc3);
    }
    float p0 = h2sumf(acc0);
    float p1 = h2sumf(acc1);
    float p2 = h2sumf(acc2);
    float p3 = h2sumf(acc3);
    p0 = fmaf(m0, xp, p0);
    p1 = fmaf(m1, xp, p1);
    p2 = fmaf(m2, xp, p2);
    p3 = fmaf(m3, xp, p3);
    p0 = qsum4(p0); p1 = qsum4(p1); p2 = qsum4(p2); p3 = qsum4(p3);

    float ig = hsig(p0), fg = hsig(p1), og = hsig(p3);
    float gg = tanh_f(p2);
    cst = fmaf(fg, cst, ig * gg);
    vh  = og * tanh_f(cst);

    if (q == 0) hlds[(t + 1) & 1][j] = __float2half(vh);
    xp = xpn;
    __syncthreads();
  }

  if (q == 0) out[b * HH + j] = vh;
}

extern "C" void kernel_launch(void* const* d_in, const int* in_sizes, int n_in,
                              void* d_out, int out_size, void* d_ws, size_t ws_size,
                              hipStream_t stream) {
  (void)in_sizes; (void)n_in; (void)out_size; (void)ws_size;

  // ---- workspace layout (~19.2 MB) ----
  // [0,16)            flag
  // [16,528)          vx fp32[128]
  // [1024, +128KB)    Uw uint[32768]  (packed f16 U pairs)
  // [+, +2MB)         newx bf16[8192*128]
  // [+, +16MB+64KB)   Xp fp32[8192*512] + one slack step (prefetch overread)
  char* ws = (char*)d_ws;
  int* flag = (int*)ws;
  float* vx = (float*)(ws + 16);
  uint* Uw = (uint*)(ws + 1024);
  __hip_bfloat16* newx = (__hip_bfloat16*)(ws + 1024 + 131072);
  float* Xp = (float*)(ws + 1024 + 131072 + (size_t)2 * 1024 * 1024);

  k_init<<<1, 128, 0, stream>>>(d_in[0], d_in[1], flag, vx);
  k_uprep<<<128, 256, 0, stream>>>(d_in[4], d_in[7], d_in[10], d_in[13], flag, Uw);
  k_pool<<<BB * TT / 2, 256, 0, stream>>>(d_in[0], flag, vx, newx);
  dim3 g2(64, 4);
  k_xproj<<<g2, 256, 0, stream>>>(newx,
      d_in[3], d_in[6], d_in[9], d_in[12],     // W_i, W_f, W_c, W_o
      d_in[5], d_in[8], d_in[11], d_in[14],    // b_i, b_f, b_c, b_o
      flag, Xp);
  k_rec<<<BB, 512, 0, stream>>>(Xp, Uw, (float*)d_out);
}